// Round 20
// baseline (109.547 us; speedup 1.0000x reference)
//
#include <hip/hip_runtime.h>
#include <hip/hip_bf16.h>

#define SEQ   64
#define BATCH 8192
#define OBS   47
#define HID   64
#define MLPH  32
#define ACT   12

#define BT 16            // batch rows per workgroup
#define NT 256           // 4 waves, merged roles: each = heavy(colset w) + xgemm(colset w)
                         // w0:+mlp1a, w1:+mlp1b, w2:+mlp2, w1-3:+obs
#define NWG (BATCH / BT) // 512 workgroups -> 2 per CU (8 waves/CU, 2/SIMD, 256 VGPR budget)

// LDS layout (bytes) — identical maps to r13/r19
#define XS0O 0           // x ping-pong [16][64] bf16 swz, 2048 each
#define XS1O 2048
#define HM0O 4096        // unmasked h ping-pong [16][64] bf16 swz, 2048 each
#define HM1O 6144
#define XA0O 8192        // xacc ping-pong: [col 64][slot 16] f32x4, 16384 each
#define XA1O 24576
#define M2EO 40960       // ELU out ping-pong [2][16][32] bf16 swzM, 1024 each
#define MSKO 43008       // masks [64][16] f32, 4096
#define W1LO 47104       // W1 frag table 4*64*16B = 4096
#define W2LO 51200       // W2 frag table 64*16B = 1024
#define SMEM_BYTES 52224

#define L2E  1.4426950408889634f
#define L2E2 2.8853900817779268f

typedef __attribute__((ext_vector_type(8))) short short8;
typedef __attribute__((ext_vector_type(4))) float f32x4;

__device__ __forceinline__ ushort f2bf(float f) {
  union { float f; unsigned u; } v; v.f = f;
  return (ushort)((v.u + 0x7FFFu + ((v.u >> 16) & 1u)) >> 16);
}
__device__ __forceinline__ float ex2(float x) {
#if __has_builtin(__builtin_amdgcn_exp2f)
  return __builtin_amdgcn_exp2f(x);
#else
  return __expf(x * 0.6931471805599453f);
#endif
}
__device__ __forceinline__ float rcpx(float x) {
#if __has_builtin(__builtin_amdgcn_rcpf)
  return __builtin_amdgcn_rcpf(x);
#else
  return __fdividef(1.0f, x);
#endif
}
__device__ __forceinline__ float sigf(float x)     { return rcpx(1.0f + ex2(-L2E * x)); }
__device__ __forceinline__ float tanhfast(float x) { return __builtin_fmaf(-2.0f, rcpx(1.0f + ex2(L2E2 * x)), 1.0f); }
// packed f32->bf16 RNE (proven contexts: H/obs/ELU writes)
__device__ __forceinline__ unsigned cvtpk(float lo, float hi) {
  unsigned r; asm("v_cvt_pk_bf16_f32 %0, %1, %2" : "=v"(r) : "v"(lo), "v"(hi)); return r;
}

// loop barrier: LDS visibility only (r10-proven sufficient)
__device__ __forceinline__ void barrier_lgkm() {
  __builtin_amdgcn_sched_barrier(0);
  asm volatile("s_waitcnt lgkmcnt(0)" ::: "memory");
  __builtin_amdgcn_s_barrier();
  __builtin_amdgcn_sched_barrier(0);
}

// XOR swizzles (bijective)
__device__ __forceinline__ int swz (int r, int ks) { return (r * 128 + ks * 2) ^ ((r & 7) << 4); }
__device__ __forceinline__ int swzM(int r, int cs) { return (r * 64  + cs * 2) ^ ((r & 7) << 4); }

extern "C" __global__ void __launch_bounds__(NT, 2)
lstm_policy(const float* __restrict__ obs, const float* __restrict__ h0,
            const float* __restrict__ c0, const float* __restrict__ Wih,
            const float* __restrict__ Whh, const float* __restrict__ bih,
            const float* __restrict__ bhh, const float* __restrict__ W1,
            const float* __restrict__ b1, const float* __restrict__ W2,
            const float* __restrict__ b2, const int* __restrict__ masks,
            float* __restrict__ out)
{
  __shared__ __align__(16) char sm[SMEM_BYTES];
  const int tid  = threadIdx.x;
  const int b0   = blockIdx.x * BT;
  const int lane = tid & 63;
  const int w    = tid >> 6;          // 0..3
  const int lr   = lane & 15;
  const int lg   = lane >> 4;         // 0..3
  const int j    = w * 16 + lr;       // owned gate/hidden column (colset = w)

  // xacc slot addresses: [col j][slot (lg*4+nf)^lr], 16B f32x4 slots (r13 layout)
  int xsl[4];
  #pragma unroll
  for (int nf = 0; nf < 4; ++nf)
    xsl[nf] = (j << 8) + ((((lg * 4 + nf) ^ lr) & 15) << 4);

  // ---------------- phase 0: zero XS, stage masks + MLP weight tables ----------------
  for (int idx = tid; idx < 256; idx += NT)          // XS0+XS1 = 4096 B
    *(f32x4*)(sm + idx * 16) = (f32x4){0.f, 0.f, 0.f, 0.f};
  for (int idx = tid; idx < SEQ * BT; idx += NT) {
    int t = idx >> 4, r = idx & 15;
    *(float*)(sm + MSKO + idx * 4) = (float)masks[t * BATCH + b0 + r];
  }
  if (tid < 64) {
    int l = tid, llr = l & 15, llg = l >> 4;
    #pragma unroll
    for (int tt = 0; tt < 2; ++tt)
      #pragma unroll
      for (int kk = 0; kk < 2; ++kk) {
        short8 f;
        const float* src = W1 + (tt * 16 + llr) * HID + kk * 32 + llg * 8;
        #pragma unroll
        for (int e = 0; e < 8; ++e) f[e] = (short)f2bf(src[e]);
        *(short8*)(sm + W1LO + ((tt * 2 + kk) * 64 + l) * 16) = f;
      }
    short8 f2;
    #pragma unroll
    for (int e = 0; e < 8; ++e)
      f2[e] = (llr < ACT) ? (short)f2bf(W2[llr * MLPH + llg * 8 + e]) : (short)0;
    *(short8*)(sm + W2LO + l * 16) = f2;
  }
  __syncthreads();

  // ---------------- phase 1: EVERY wave builds whh + wih frags; state; obs ----------------
  short8 whh[4][2], wih[4][2];     // 64 short8 total = fits 256-reg budget, no spill
  float biasg[4];
  float creg[4] = {0, 0, 0, 0}, hlast[4] = {0, 0, 0, 0};
  int shw[4];
  #pragma unroll
  for (int q = 0; q < 4; ++q) shw[q] = swz(lg * 4 + q, j);

  #pragma unroll
  for (int nf = 0; nf < 4; ++nf) {
    int n = nf * 64 + j;
    biasg[nf] = bih[n] + bhh[n];
    #pragma unroll
    for (int kk = 0; kk < 2; ++kk) {
      const float* src = Whh + n * HID + kk * 32 + lg * 8;
      short8 f;
      #pragma unroll
      for (int e = 0; e < 8; ++e) f[e] = (short)f2bf(src[e]);
      whh[nf][kk] = f;
      short8 g;
      #pragma unroll
      for (int e = 0; e < 8; ++e) {
        int k = kk * 32 + lg * 8 + e;
        g[e] = (k < OBS) ? (short)f2bf(Wih[n * OBS + k]) : (short)0;
      }
      wih[nf][kk] = g;
    }
  }
  #pragma unroll
  for (int q = 0; q < 4; ++q) {
    int r = lg * 4 + q;
    creg[q] = c0[(size_t)(b0 + r) * HID + j];                               // unmasked
    *(ushort*)(sm + HM0O + shw[q]) = f2bf(h0[(size_t)(b0 + r) * HID + j]);  // unmasked
  }

  float b1v = 0.f, b2v = 0.f;
  if (w == 0) b1v = b1[lr];               // mlp1 half 0 (cols 0-15)
  if (w == 1) b1v = b1[16 + lr];          // mlp1 half 1 (cols 16-31)
  if (w == 2) b2v = (lr < ACT) ? b2[lr] : 0.f;

  // obs staging: waves 1-3 (tid 64..251), 188 slots of f32x4 cover 16*47 = 752 floats
  const int oidx = tid - 64;
  const bool oact = (oidx >= 0) && (oidx < 188);
  int a_obs[4] = {0, 0, 0, 0};
  f32x4 ovh = {0.f, 0.f, 0.f, 0.f};
  const float* obsp = obs;
  if (oact) {
    #pragma unroll
    for (int e = 0; e < 4; ++e) {
      int flat = oidx * 4 + e;
      int r = flat / OBS, k = flat - OBS * r;
      a_obs[e] = swz(r, k);
    }
    f32x4 v0 = *(const f32x4*)(obs + (size_t)b0 * OBS + oidx * 4);               // x(0)
    f32x4 v1 = *(const f32x4*)(obs + ((size_t)BATCH + b0) * OBS + oidx * 4);     // x(1)
    #pragma unroll
    for (int e = 0; e < 4; ++e) *(ushort*)(sm + XS0O + a_obs[e]) = f2bf(v0[e]);
    #pragma unroll
    for (int e = 0; e < 4; ++e) *(ushort*)(sm + XS1O + a_obs[e]) = f2bf(v1[e]);
    obsp = obs + ((size_t)2 * BATCH + b0) * OBS + oidx * 4;
    ovh = *(const f32x4*)(obsp);                                                 // x(2)
    obsp += (size_t)BATCH * OBS;
  }
  __syncthreads();

  // ---------------- x-GEMM (ALL waves, own colset): xacc = x@Wih^T + b, f32 direct ----------------
  auto do_xgemm = [&](int B) {
    const int xsb = B ? XS1O : XS0O;
    const int xab = B ? XA1O : XA0O;
    short8 ax0 = *(const short8*)(sm + xsb + swz(lr, lg * 8));
    short8 ax1 = *(const short8*)(sm + xsb + swz(lr, 32 + lg * 8));
    #pragma unroll
    for (int nf = 0; nf < 4; ++nf) {
      f32x4 a = (f32x4){biasg[nf], biasg[nf], biasg[nf], biasg[nf]};
      a = __builtin_amdgcn_mfma_f32_16x16x32_bf16(ax0, wih[nf][0], a, 0, 0, 0);
      a = __builtin_amdgcn_mfma_f32_16x16x32_bf16(ax1, wih[nf][1], a, 0, 0, 0);
      *(f32x4*)(sm + xab + xsl[nf]) = a;     // straight b128 store, no pack
    }
  };

  do_xgemm(0);    // xacc(0) — all 4 colsets covered (wave w = colset w)
  __syncthreads();

  // ---------------- MLP layer 1 half (waves 0/1): ELU(h(TT)@W1^T+b1)[half] -> M2E[TT&1] ----------------
  auto do_mlp1h = [&](int TT, int HMB, int half) {
    const int me = M2EO + (TT & 1) * 1024;
    short8 hf0 = *(const short8*)(sm + HMB + swz(lr, lg * 8));
    short8 hf1 = *(const short8*)(sm + HMB + swz(lr, 32 + lg * 8));
    f32x4 am = (f32x4){b1v, b1v, b1v, b1v};
    short8 wA;
    wA = *(const short8*)(sm + W1LO + ((half * 2 + 0) * 64 + lane) * 16);
    am = __builtin_amdgcn_mfma_f32_16x16x32_bf16(hf0, wA, am, 0, 0, 0);
    wA = *(const short8*)(sm + W1LO + ((half * 2 + 1) * 64 + lane) * 16);
    am = __builtin_amdgcn_mfma_f32_16x16x32_bf16(hf1, wA, am, 0, 0, 0);
    float e[4];
    #pragma unroll
    for (int q = 0; q < 4; ++q) {
      float v = am[q];
      e[q] = v > 0.f ? v : (ex2(L2E * v) - 1.f);
    }
    unsigned u01 = cvtpk(e[0], e[1]);
    unsigned u23 = cvtpk(e[2], e[3]);
    const int c = half * 16 + lr;
    *(ushort*)(sm + me + swzM(lg * 4 + 0, c)) = (ushort)u01;
    *(ushort*)(sm + me + swzM(lg * 4 + 1, c)) = (ushort)(u01 >> 16);
    *(ushort*)(sm + me + swzM(lg * 4 + 2, c)) = (ushort)u23;
    *(ushort*)(sm + me + swzM(lg * 4 + 3, c)) = (ushort)(u23 >> 16);
  };

  // ---------------- MLP layer 2 (wave 2): M2E[TT&1]@W2^T + b2 -> means(TT) ----------------
  auto do_mlp2 = [&](int TT) {
    const int me = M2EO + (TT & 1) * 1024;
    f32x4 a2 = (f32x4){b2v, b2v, b2v, b2v};
    short8 ef  = *(const short8*)(sm + me + swzM(lr, lg * 8));
    short8 w2f = *(const short8*)(sm + W2LO + lane * 16);
    a2 = __builtin_amdgcn_mfma_f32_16x16x32_bf16(ef, w2f, a2, 0, 0, 0);
    if (lr < ACT) {
      float* op = out + ((size_t)TT * BATCH + b0 + lg * 4) * ACT + lr;
      #pragma unroll
      for (int q = 0; q < 4; ++q) op[q * ACT] = a2[q];
    }
  };

  // ---------------- one step (parity P = T&1): ONE lgkm barrier ----------------
  // ALL waves: heavy (HM[P], XA[P] -> cell -> HM[P^1]) + xgemm(T+1: XS[P^1]->XA[P^1]).
  // w0: + mlp1-half0(T-1).  w1: + mlp1-half1(T-1).  w2: + mlp2(T-2).
  // waves 1-3 (oact): + obs commit x(T+2)->XS[P], prefetch x(T+3).
  auto do_step = [&](int P, int T) {
    const int hmr = P ? HM1O : HM0O;
    const int hmw = P ? HM0O : HM1O;
    const int xar = P ? XA1O : XA0O;
    short8 ah0 = *(const short8*)(sm + hmr + swz(lr, lg * 8));
    short8 ah1 = *(const short8*)(sm + hmr + swz(lr, 32 + lg * 8));
    f32x4 xq0 = *(const f32x4*)(sm + xar + xsl[0]);
    f32x4 xq1 = *(const f32x4*)(sm + xar + xsl[1]);
    f32x4 xq2 = *(const f32x4*)(sm + xar + xsl[2]);
    f32x4 xq3 = *(const f32x4*)(sm + xar + xsl[3]);
    const f32x4 z = {0.f, 0.f, 0.f, 0.f};
    // 8 independent MFMAs, then vector sums (r13-proven)
    f32x4 pa0 = __builtin_amdgcn_mfma_f32_16x16x32_bf16(ah0, whh[0][0], z, 0, 0, 0);
    f32x4 pa1 = __builtin_amdgcn_mfma_f32_16x16x32_bf16(ah0, whh[1][0], z, 0, 0, 0);
    f32x4 pa2 = __builtin_amdgcn_mfma_f32_16x16x32_bf16(ah0, whh[2][0], z, 0, 0, 0);
    f32x4 pa3 = __builtin_amdgcn_mfma_f32_16x16x32_bf16(ah0, whh[3][0], z, 0, 0, 0);
    f32x4 pb0 = __builtin_amdgcn_mfma_f32_16x16x32_bf16(ah1, whh[0][1], z, 0, 0, 0);
    f32x4 pb1 = __builtin_amdgcn_mfma_f32_16x16x32_bf16(ah1, whh[1][1], z, 0, 0, 0);
    f32x4 pb2 = __builtin_amdgcn_mfma_f32_16x16x32_bf16(ah1, whh[2][1], z, 0, 0, 0);
    f32x4 pb3 = __builtin_amdgcn_mfma_f32_16x16x32_bf16(ah1, whh[3][1], z, 0, 0, 0);

    f32x4 mc = *(const f32x4*)(sm + MSKO + (T << 6) + (lg << 4));   // m(T)
    f32x4 g0 = xq0 + mc * (pa0 + pb0);
    f32x4 g1 = xq1 + mc * (pa1 + pb1);
    f32x4 g2 = xq2 + mc * (pa2 + pb2);
    f32x4 g3 = xq3 + mc * (pa3 + pb3);

    float hq[4];
    #pragma unroll
    for (int q = 0; q < 4; ++q) {
      float iv = sigf(g0[q]);
      float fv = sigf(g1[q]);
      float gv = tanhfast(g2[q]);
      float ov = sigf(g3[q]);
      float c  = fv * (creg[q] * mc[q]) + iv * gv;
      float h  = ov * tanhfast(c);
      creg[q]  = c;                                   // unmasked
      hlast[q] = h;
      hq[q]    = h;
    }
    unsigned u01 = cvtpk(hq[0], hq[1]);
    unsigned u23 = cvtpk(hq[2], hq[3]);
    *(ushort*)(sm + hmw + shw[0]) = (ushort)u01;
    *(ushort*)(sm + hmw + shw[1]) = (ushort)(u01 >> 16);
    *(ushort*)(sm + hmw + shw[2]) = (ushort)u23;
    *(ushort*)(sm + hmw + shw[3]) = (ushort)(u23 >> 16);

    if (T + 1 < SEQ) do_xgemm(P ^ 1);   // second independent chain, same wave

    if (w == 0) {
      if (T > 0) do_mlp1h(T - 1, hmr, 0);             // h(T-1) in HM[P]
    } else if (w == 1) {
      if (T > 0) do_mlp1h(T - 1, hmr, 1);
    } else if (w == 2) {
      if (T > 1) do_mlp2(T - 2);                      // M2E[(T-2)&1] = M2E[P]
    }
    if (oact) {
      f32x4 ovn = ovh;
      if (T + 3 < SEQ) { ovn = *(const f32x4*)(obsp); }
      obsp += (size_t)BATCH * OBS;
      if (T + 2 < SEQ) {
        const int xsw = P ? XS1O : XS0O;
        unsigned p0 = cvtpk(ovh[0], ovh[1]), p1 = cvtpk(ovh[2], ovh[3]);
        *(ushort*)(sm + xsw + a_obs[0]) = (ushort)p0;
        *(ushort*)(sm + xsw + a_obs[1]) = (ushort)(p0 >> 16);
        *(ushort*)(sm + xsw + a_obs[2]) = (ushort)p1;
        *(ushort*)(sm + xsw + a_obs[3]) = (ushort)(p1 >> 16);
      }
      ovh = ovn;
    }
    barrier_lgkm();
  };

  for (int t = 0; t < SEQ; t += 2) {
    do_step(0, t);
    do_step(1, t + 1);
  }
  // tail: h(63) is in HM0 (step 63 wrote HM[P^1]=HM[0]); M2E[0] holds mlp1(62).
  if (w == 0)      do_mlp1h(63, HM0O, 0);
  else if (w == 1) do_mlp1h(63, HM0O, 1);
  else if (w == 2) do_mlp2(62);
  barrier_lgkm();
  if (w == 2) do_mlp2(63);    // M2E[1] = mlp1(63)

  // ---------------- final h, c (each wave owns rows lg*4+q, col j) ----------------
  {
    float* hout = out + (size_t)SEQ * BATCH * ACT;
    float* cout = hout + (size_t)BATCH * HID;
    #pragma unroll
    for (int q = 0; q < 4; ++q) {
      int r = lg * 4 + q;
      hout[(size_t)(b0 + r) * HID + j] = hlast[q];   // h(63) unmasked
      cout[(size_t)(b0 + r) * HID + j] = creg[q];    // c(63) unmasked
    }
  }
}

extern "C" void kernel_launch(void* const* d_in, const int* in_sizes, int n_in,
                              void* d_out, int out_size, void* d_ws, size_t ws_size,
                              hipStream_t stream) {
  (void)in_sizes; (void)n_in; (void)d_ws; (void)ws_size; (void)out_size;
  lstm_policy<<<dim3(NWG), dim3(NT), 0, stream>>>(
      (const float*)d_in[0], (const float*)d_in[1], (const float*)d_in[2],
      (const float*)d_in[3], (const float*)d_in[4], (const float*)d_in[5],
      (const float*)d_in[6], (const float*)d_in[7], (const float*)d_in[8],
      (const float*)d_in[9], (const float*)d_in[10], (const int*)d_in[11],
      (float*)d_out);
}

// Round 21
// 97.919 us; speedup vs baseline: 1.1188x; 1.1188x over previous
//
#include <hip/hip_runtime.h>
#include <hip/hip_bf16.h>

#define SEQ   64
#define BATCH 8192
#define OBS   47
#define HID   64
#define MLPH  32
#define ACT   12

#define BT 16            // batch rows per workgroup
#define NT 512           // 8 waves: 0-3 heavy (h-GEMM+cell), 4-7 light (x-GEMM; 4:+MLP, 5-7:+obs)
#define NWG (BATCH / BT) // 512 workgroups -> 2 per CU

// LDS layout (bytes)
#define XS0O 0           // x ping-pong [16][64] bf16 swz, 2048 each
#define XS1O 2048
#define HM0O 4096        // unmasked h ping-pong [16][64] bf16 swz, 2048 each
#define HM1O 6144
#define XA0O 8192        // xacc ping-pong: [col 64][slot 16] f32x4, 16384 each
#define XA1O 24576
#define M2OO 40960       // wave-4 ELU scratch [16][32] bf16 swzM, 1024
#define MSKO 41984       // masks [64][16] f32, 4096
#define W1LO 46080       // W1 frag table 4*64*16B = 4096
#define W2LO 50176       // W2 frag table 64*16B = 1024
#define SMEM_BYTES 51200

#define L2E  1.4426950408889634f
#define L2E2 2.8853900817779268f

typedef __attribute__((ext_vector_type(8))) short short8;
typedef __attribute__((ext_vector_type(4))) float f32x4;

__device__ __forceinline__ ushort f2bf(float f) {
  union { float f; unsigned u; } v; v.f = f;
  return (ushort)((v.u + 0x7FFFu + ((v.u >> 16) & 1u)) >> 16);
}
// native 2^x / 1/x with compiler-managed hazards; fall back to r12's exact path
__device__ __forceinline__ float ex2(float x) {
#if __has_builtin(__builtin_amdgcn_exp2f)
  return __builtin_amdgcn_exp2f(x);
#else
  return __expf(x * 0.6931471805599453f);
#endif
}
__device__ __forceinline__ float rcpx(float x) {
#if __has_builtin(__builtin_amdgcn_rcpf)
  return __builtin_amdgcn_rcpf(x);
#else
  return __fdividef(1.0f, x);
#endif
}
// sigma(x) = 1/(1+2^(-L2E x));  tanh(x) = 1 - 2/(1+2^(2 L2E x))
__device__ __forceinline__ float sigf(float x)     { return rcpx(1.0f + ex2(-L2E * x)); }
__device__ __forceinline__ float tanhfast(float x) { return __builtin_fmaf(-2.0f, rcpx(1.0f + ex2(L2E2 * x)), 1.0f); }
// packed f32->bf16 RNE (proven r11/r12)
__device__ __forceinline__ unsigned cvtpk(float lo, float hi) {
  unsigned r; asm("v_cvt_pk_bf16_f32 %0, %1, %2" : "=v"(r) : "v"(lo), "v"(hi)); return r;
}

// loop barrier: LDS visibility only (proven r10-neutral; semantics sufficient)
__device__ __forceinline__ void barrier_lgkm() {
  __builtin_amdgcn_sched_barrier(0);
  asm volatile("s_waitcnt lgkmcnt(0)" ::: "memory");
  __builtin_amdgcn_s_barrier();
  __builtin_amdgcn_sched_barrier(0);
}

// XOR swizzles (bijective)
__device__ __forceinline__ int swz (int r, int ks) { return (r * 128 + ks * 2) ^ ((r & 7) << 4); }
__device__ __forceinline__ int swzM(int r, int cs) { return (r * 64  + cs * 2) ^ ((r & 7) << 4); }

extern "C" __global__ void __launch_bounds__(NT, 4)
lstm_policy(const float* __restrict__ obs, const float* __restrict__ h0,
            const float* __restrict__ c0, const float* __restrict__ Wih,
            const float* __restrict__ Whh, const float* __restrict__ bih,
            const float* __restrict__ bhh, const float* __restrict__ W1,
            const float* __restrict__ b1, const float* __restrict__ W2,
            const float* __restrict__ b2, const int* __restrict__ masks,
            float* __restrict__ out)
{
  __shared__ __align__(16) char sm[SMEM_BYTES];
  const int tid  = threadIdx.x;
  const int b0   = blockIdx.x * BT;
  const int lane = tid & 63;
  const int w    = tid >> 6;          // 0..7
  const int lr   = lane & 15;
  const int lg   = lane >> 4;         // 0..3
  const int j    = (w & 3) * 16 + lr; // owned gate/hidden column (col-set = w&3)

  // xacc slot addresses: [col j][slot (lg*4+nf)^lr], 16B f32x4 slots (r12 layout)
  int xsl[4];
  #pragma unroll
  for (int nf = 0; nf < 4; ++nf)
    xsl[nf] = (j << 8) + ((((lg * 4 + nf) ^ lr) & 15) << 4);

  // ---------------- phase 0: zero XS, stage masks + MLP weight tables ----------------
  for (int idx = tid; idx < 256; idx += NT)          // XS0+XS1 = 4096 B
    *(f32x4*)(sm + idx * 16) = (f32x4){0.f, 0.f, 0.f, 0.f};
  for (int idx = tid; idx < SEQ * BT; idx += NT) {
    int t = idx >> 4, r = idx & 15;
    *(float*)(sm + MSKO + idx * 4) = (float)masks[t * BATCH + b0 + r];
  }
  if (tid < 64) {
    int l = tid, llr = l & 15, llg = l >> 4;
    #pragma unroll
    for (int tt = 0; tt < 2; ++tt)
      #pragma unroll
      for (int kk = 0; kk < 2; ++kk) {
        short8 f;
        const float* src = W1 + (tt * 16 + llr) * HID + kk * 32 + llg * 8;
        #pragma unroll
        for (int e = 0; e < 8; ++e) f[e] = (short)f2bf(src[e]);
        *(short8*)(sm + W1LO + ((tt * 2 + kk) * 64 + l) * 16) = f;
      }
    short8 f2;
    #pragma unroll
    for (int e = 0; e < 8; ++e)
      f2[e] = (llr < ACT) ? (short)f2bf(W2[llr * MLPH + llg * 8 + e]) : (short)0;
    *(short8*)(sm + W2LO + l * 16) = f2;
  }
  __syncthreads();

  // ---------------- phase 1: register builds + initial staging ----------------
  short8 wf[4][2];                 // heavy: Whh frags ; light: Wih frags
  float biasg[4] = {0, 0, 0, 0};
  float creg[4] = {0, 0, 0, 0}, hlast[4] = {0, 0, 0, 0};
  int shw[4];                      // h-write swizzled offsets
  #pragma unroll
  for (int q = 0; q < 4; ++q) shw[q] = swz(lg * 4 + q, j);

  if (w < 4) {
    #pragma unroll
    for (int nf = 0; nf < 4; ++nf) {
      int n = nf * 64 + j;
      #pragma unroll
      for (int kk = 0; kk < 2; ++kk) {
        const float* src = Whh + n * HID + kk * 32 + lg * 8;
        short8 f;
        #pragma unroll
        for (int e = 0; e < 8; ++e) f[e] = (short)f2bf(src[e]);
        wf[nf][kk] = f;
      }
    }
    #pragma unroll
    for (int q = 0; q < 4; ++q) {
      int r = lg * 4 + q;
      creg[q] = c0[(size_t)(b0 + r) * HID + j];                               // unmasked
      *(ushort*)(sm + HM0O + shw[q]) = f2bf(h0[(size_t)(b0 + r) * HID + j]);  // unmasked
    }
  } else {
    #pragma unroll
    for (int nf = 0; nf < 4; ++nf) {
      int n = nf * 64 + j;
      biasg[nf] = bih[n] + bhh[n];
      #pragma unroll
      for (int kk = 0; kk < 2; ++kk) {
        short8 f;
        #pragma unroll
        for (int e = 0; e < 8; ++e) {
          int k = kk * 32 + lg * 8 + e;
          f[e] = (k < OBS) ? (short)f2bf(Wih[n * OBS + k]) : (short)0;
        }
        wf[nf][kk] = f;
      }
    }
  }

  float b1v0 = 0.f, b1v1 = 0.f, b2v = 0.f;
  float* outp = out + ((size_t)(b0 + lg * 4)) * ACT + lr;   // wave-4 running out ptr
  if (w == 4) { b1v0 = b1[lr]; b1v1 = b1[16 + lr]; b2v = (lr < ACT) ? b2[lr] : 0.f; }

  // obs staging lanes: waves 5-7, 188 slots of f32x4 cover 16*47 floats
  const int oidx = tid - 320;
  const bool oact = (w >= 5) && (oidx >= 0) && (oidx < 188);
  int a_obs[4] = {0, 0, 0, 0};
  f32x4 ovh = {0.f, 0.f, 0.f, 0.f};
  const float* obsp = obs;
  if (oact) {
    #pragma unroll
    for (int e = 0; e < 4; ++e) {
      int flat = oidx * 4 + e;
      int r = flat / OBS, k = flat - OBS * r;
      a_obs[e] = swz(r, k);
    }
    f32x4 v0 = *(const f32x4*)(obs + (size_t)b0 * OBS + oidx * 4);               // x(0)
    f32x4 v1 = *(const f32x4*)(obs + ((size_t)BATCH + b0) * OBS + oidx * 4);     // x(1)
    #pragma unroll
    for (int e = 0; e < 4; ++e) *(ushort*)(sm + XS0O + a_obs[e]) = f2bf(v0[e]);
    #pragma unroll
    for (int e = 0; e < 4; ++e) *(ushort*)(sm + XS1O + a_obs[e]) = f2bf(v1[e]);
    obsp = obs + ((size_t)2 * BATCH + b0) * OBS + oidx * 4;
    ovh = *(const f32x4*)(obsp);                                                 // x(2)
    obsp += (size_t)BATCH * OBS;
  }
  __syncthreads();

  // ---------------- light x-GEMM: xacc(buf B) = x@Wih^T + b, f32 direct ----------------
  auto do_xgemm = [&](int B) {
    const int xsb = B ? XS1O : XS0O;
    const int xab = B ? XA1O : XA0O;
    short8 ax0 = *(const short8*)(sm + xsb + swz(lr, lg * 8));
    short8 ax1 = *(const short8*)(sm + xsb + swz(lr, 32 + lg * 8));
    #pragma unroll
    for (int nf = 0; nf < 4; ++nf) {
      f32x4 a = (f32x4){biasg[nf], biasg[nf], biasg[nf], biasg[nf]};
      a = __builtin_amdgcn_mfma_f32_16x16x32_bf16(ax0, wf[nf][0], a, 0, 0, 0);
      a = __builtin_amdgcn_mfma_f32_16x16x32_bf16(ax1, wf[nf][1], a, 0, 0, 0);
      *(f32x4*)(sm + xab + xsl[nf]) = a;     // straight b128 store, no pack
    }
  };

  if (w >= 4) do_xgemm(0);    // xacc(0)
  __syncthreads();

  // ---------------- MLP (wave 4): means from HM[P] ----------------
  auto do_mlp = [&](int P) {
    const int hmb = P ? HM1O : HM0O;
    short8 hf0 = *(const short8*)(sm + hmb + swz(lr, lg * 8));
    short8 hf1 = *(const short8*)(sm + hmb + swz(lr, 32 + lg * 8));
    f32x4 am0 = (f32x4){b1v0, b1v0, b1v0, b1v0};
    f32x4 am1 = (f32x4){b1v1, b1v1, b1v1, b1v1};
    short8 wA;
    wA = *(const short8*)(sm + W1LO + (0 * 64 + lane) * 16);
    am0 = __builtin_amdgcn_mfma_f32_16x16x32_bf16(hf0, wA, am0, 0, 0, 0);
    wA = *(const short8*)(sm + W1LO + (1 * 64 + lane) * 16);
    am0 = __builtin_amdgcn_mfma_f32_16x16x32_bf16(hf1, wA, am0, 0, 0, 0);
    wA = *(const short8*)(sm + W1LO + (2 * 64 + lane) * 16);
    am1 = __builtin_amdgcn_mfma_f32_16x16x32_bf16(hf0, wA, am1, 0, 0, 0);
    wA = *(const short8*)(sm + W1LO + (3 * 64 + lane) * 16);
    am1 = __builtin_amdgcn_mfma_f32_16x16x32_bf16(hf1, wA, am1, 0, 0, 0);
    #pragma unroll
    for (int q = 0; q < 4; ++q) {
      int r = lg * 4 + q;
      float v0 = am0[q], v1 = am1[q];
      float e0 = v0 > 0.f ? v0 : (ex2(L2E * v0) - 1.f);
      float e1 = v1 > 0.f ? v1 : (ex2(L2E * v1) - 1.f);
      unsigned u = cvtpk(e0, e1);
      *(ushort*)(sm + M2OO + swzM(r, lr))      = (ushort)u;
      *(ushort*)(sm + M2OO + swzM(r, 16 + lr)) = (ushort)(u >> 16);
    }
    f32x4 a2 = (f32x4){b2v, b2v, b2v, b2v};   // same-wave LDS RAW: in-order DS
    short8 ef  = *(const short8*)(sm + M2OO + swzM(lr, lg * 8));
    short8 w2f = *(const short8*)(sm + W2LO + lane * 16);
    a2 = __builtin_amdgcn_mfma_f32_16x16x32_bf16(ef, w2f, a2, 0, 0, 0);
    if (lr < ACT) {
      #pragma unroll
      for (int q = 0; q < 4; ++q) outp[q * ACT] = a2[q];
    }
    outp += (size_t)BATCH * ACT;
  };

  // ---------------- one step (parity P = T&1): ONE lgkm barrier ----------------
  auto do_step = [&](int P, int T) {
    if (w < 4) {
      __builtin_amdgcn_s_setprio(1);     // T5 (in winning r12 config)
      const int hmr = P ? HM1O : HM0O;
      const int hmw = P ? HM0O : HM1O;
      const int xar = P ? XA1O : XA0O;
      short8 ah0 = *(const short8*)(sm + hmr + swz(lr, lg * 8));
      short8 ah1 = *(const short8*)(sm + hmr + swz(lr, 32 + lg * 8));
      f32x4 xq0 = *(const f32x4*)(sm + xar + xsl[0]);
      f32x4 xq1 = *(const f32x4*)(sm + xar + xsl[1]);
      f32x4 xq2 = *(const f32x4*)(sm + xar + xsl[2]);
      f32x4 xq3 = *(const f32x4*)(sm + xar + xsl[3]);
      const f32x4 z = {0.f, 0.f, 0.f, 0.f};
      // 8 independent MFMAs (no 2-deep acc chains), then vector sums
      f32x4 pa0 = __builtin_amdgcn_mfma_f32_16x16x32_bf16(ah0, wf[0][0], z, 0, 0, 0);
      f32x4 pa1 = __builtin_amdgcn_mfma_f32_16x16x32_bf16(ah0, wf[1][0], z, 0, 0, 0);
      f32x4 pa2 = __builtin_amdgcn_mfma_f32_16x16x32_bf16(ah0, wf[2][0], z, 0, 0, 0);
      f32x4 pa3 = __builtin_amdgcn_mfma_f32_16x16x32_bf16(ah0, wf[3][0], z, 0, 0, 0);
      f32x4 pb0 = __builtin_amdgcn_mfma_f32_16x16x32_bf16(ah1, wf[0][1], z, 0, 0, 0);
      f32x4 pb1 = __builtin_amdgcn_mfma_f32_16x16x32_bf16(ah1, wf[1][1], z, 0, 0, 0);
      f32x4 pb2 = __builtin_amdgcn_mfma_f32_16x16x32_bf16(ah1, wf[2][1], z, 0, 0, 0);
      f32x4 pb3 = __builtin_amdgcn_mfma_f32_16x16x32_bf16(ah1, wf[3][1], z, 0, 0, 0);

      f32x4 mc = *(const f32x4*)(sm + MSKO + (T << 6) + (lg << 4));   // m(T)
      // vectorized gate math (packed-f32 capable)
      f32x4 g0 = xq0 + mc * (pa0 + pb0);
      f32x4 g1 = xq1 + mc * (pa1 + pb1);
      f32x4 g2 = xq2 + mc * (pa2 + pb2);
      f32x4 g3 = xq3 + mc * (pa3 + pb3);

      float hq[4];
      #pragma unroll
      for (int q = 0; q < 4; ++q) {
        float iv = sigf(g0[q]);
        float fv = sigf(g1[q]);
        float gv = tanhfast(g2[q]);
        float ov = sigf(g3[q]);
        float c  = fv * (creg[q] * mc[q]) + iv * gv;
        float h  = ov * tanhfast(c);
        creg[q]  = c;                                   // unmasked
        hlast[q] = h;
        hq[q]    = h;
      }
      unsigned u01 = cvtpk(hq[0], hq[1]);
      unsigned u23 = cvtpk(hq[2], hq[3]);
      *(ushort*)(sm + hmw + shw[0]) = (ushort)u01;
      *(ushort*)(sm + hmw + shw[1]) = (ushort)(u01 >> 16);
      *(ushort*)(sm + hmw + shw[2]) = (ushort)u23;
      *(ushort*)(sm + hmw + shw[3]) = (ushort)(u23 >> 16);
      __builtin_amdgcn_s_setprio(0);
    } else {
      if (T + 1 < SEQ) do_xgemm(P ^ 1);
      if (w == 4) {
        if (T > 0) do_mlp(P);            // means(T-1)
      } else if (oact) {
        f32x4 ovn = ovh;
        if (T + 3 < SEQ) { ovn = *(const f32x4*)(obsp); }
        obsp += (size_t)BATCH * OBS;
        if (T + 2 < SEQ) {
          const int xsw = P ? XS1O : XS0O;
          unsigned p0 = cvtpk(ovh[0], ovh[1]), p1 = cvtpk(ovh[2], ovh[3]);
          *(ushort*)(sm + xsw + a_obs[0]) = (ushort)p0;
          *(ushort*)(sm + xsw + a_obs[1]) = (ushort)(p0 >> 16);
          *(ushort*)(sm + xsw + a_obs[2]) = (ushort)p1;
          *(ushort*)(sm + xsw + a_obs[3]) = (ushort)(p1 >> 16);
        }
        ovh = ovn;
      }
    }
    barrier_lgkm();   // LDS-visibility barrier; global loads stay in flight
  };

  for (int t = 0; t < SEQ; t += 2) {
    do_step(0, t);
    do_step(1, t + 1);
  }
  if (w == 4) do_mlp(0);      // means(63): h(63) is in HM0

  // ---------------- final h, c ----------------
  if (w < 4) {
    float* hout = out + (size_t)SEQ * BATCH * ACT;
    float* cout = hout + (size_t)BATCH * HID;
    #pragma unroll
    for (int q = 0; q < 4; ++q) {
      int r = lg * 4 + q;
      hout[(size_t)(b0 + r) * HID + j] = hlast[q];   // h(63) unmasked
      cout[(size_t)(b0 + r) * HID + j] = creg[q];    // c(63) unmasked
    }
  }
}

extern "C" void kernel_launch(void* const* d_in, const int* in_sizes, int n_in,
                              void* d_out, int out_size, void* d_ws, size_t ws_size,
                              hipStream_t stream) {
  (void)in_sizes; (void)n_in; (void)d_ws; (void)ws_size; (void)out_size;
  lstm_policy<<<dim3(NWG), dim3(NT), 0, stream>>>(
      (const float*)d_in[0], (const float*)d_in[1], (const float*)d_in[2],
      (const float*)d_in[3], (const float*)d_in[4], (const float*)d_in[5],
      (const float*)d_in[6], (const float*)d_in[7], (const float*)d_in[8],
      (const float*)d_in[9], (const float*)d_in[10], (const int*)d_in[11],
      (float*)d_out);
}